// Round 16
// baseline (260.709 us; speedup 1.0000x reference)
//
#include <hip/hip_runtime.h>

#define TT 512
#define BB 1024
#define FF 16
#define HH 32
#define OO 8
#define SPW 8              // sequences per wave

typedef _Float16 f16;
typedef f16 v8h __attribute__((ext_vector_type(8)));
typedef float f32x4 __attribute__((ext_vector_type(4)));
typedef int  v4i __attribute__((ext_vector_type(4)));

__device__ __forceinline__ float rcp_fast(float x){ return __builtin_amdgcn_rcpf(x); }
// inputs PRE-SCALED by log2e (resp. 2*log2e) -> plain exp2
__device__ __forceinline__ float sigm2(float y){
    return rcp_fast(1.0f + __builtin_amdgcn_exp2f(-y));
}
__device__ __forceinline__ int pkh(float a, float b){
    return __builtin_bit_cast(int, __builtin_amdgcn_cvt_pkrtz(a, b));
}
__device__ __forceinline__ int bperm(int addr, int v){
    return __builtin_amdgcn_ds_bpermute(addr, v);
}

// ---- one unit-slot: 4 MFMAs (K=64 via 2 chained) + activation ----
// D layout (validated r8/r9): col=lane&15, row=(lane>>4)*4+reg.
// A rows are unit-interleaved: row R -> gate=R&3, unit=4*(R>>4)+((R>>2)&3),
// so acc[T] = (i,f,g,o) preactivation of unit 4T+gt at col lane&15.
// cb selects tile pair (even: units 0-15, odd: units 16-31) of the
// duplicated column -> 4 cndmask, no cross-lane moves.
#define UNITSTEP(N, CP, HO)                                                    \
  {                                                                            \
    f32x4 uA = __builtin_amdgcn_mfma_f32_16x16x32_f16(aw0[N], b0, Cb[N],0,0,0);\
    uA = __builtin_amdgcn_mfma_f32_16x16x32_f16(aw1[N], b1, uA, 0,0,0);        \
    f32x4 uB = __builtin_amdgcn_mfma_f32_16x16x32_f16(aw0[4+(N)], b0,          \
                                                      Cb[4+(N)], 0,0,0);       \
    uB = __builtin_amdgcn_mfma_f32_16x16x32_f16(aw1[4+(N)], b1, uB, 0,0,0);    \
    const float gi = cb ? uB[0] : uA[0];                                       \
    const float gf = cb ? uB[1] : uA[1];                                       \
    const float gg = cb ? uB[2] : uA[2];                                       \
    const float go = cb ? uB[3] : uA[3];                                       \
    const float si = sigm2(gi), sf = sigm2(gf);                                \
    const float sg = sigm2(gg), so = sigm2(go);                                \
    const float tgp = fmaf(sg, 2.0f * L2E2, -L2E2);   /* 2log2e*tanh(g) */     \
    CP = fmaf(sf, CP, si * tgp);                      /* cp = 2log2e*c  */     \
    HO = so * fmaf(2.0f, sigm2(CP), -1.0f);           /* so*tanh(c)     */     \
  }

// ---- one timestep for all 8 sequences ----
// Gather prev-step h into B fragments with 4 ds_bpermute (per-g source
// lanes precomputed); x comes from a 2-step-deep register prefetch.
#define STEP(F0, F1, NVALID)                                                   \
  {                                                                            \
    const int q0 = bperm(aAdr, pkL), q1 = bperm(aAdr, pkH);                    \
    const int q2 = bperm(bAdr, pkL), q3 = bperm(bAdr, pkH);                    \
    const int x0 = pkh(F0.x, F0.y), x1 = pkh(F0.z, F0.w);                      \
    const int x2 = pkh(F1.x, F1.y), x3 = pkh(F1.z, F1.w);                      \
    if (NVALID) { F0 = *(const float4*)xp; F1 = *(const float4*)(xp + 4);      \
                  xp += tstep; }                                               \
    v4i b0i = (v4i){ sel2 ? x0 : q0, sel2 ? x1 : q1,                           \
                     sel2 ? x2 : q2, sel2 ? x3 : q3 };                         \
    v4i b1i = (v4i){ sel2 ? q0 : 0, sel2 ? q1 : 0,                             \
                     sel2 ? q2 : 0, sel2 ? q3 : 0 };                           \
    const v8h b0 = __builtin_bit_cast(v8h, b0i);                               \
    const v8h b1 = __builtin_bit_cast(v8h, b1i);                               \
    UNITSTEP(0, cp0, h0)                                                       \
    UNITSTEP(1, cp1, h1)                                                       \
    UNITSTEP(2, cp2, h2)                                                       \
    UNITSTEP(3, cp3, h3)                                                       \
    pkL = pkh(h0, h1); pkH = pkh(h2, h3);                                      \
  }

// One wave = 8 contiguous batch rows of one direction (256 blocks, 1/CU).
// Per step: 16 MFMA (K=64: x(16)+h(32, K-permuted)+pad; bias via C) compute
// all 8 seqs' 128 gate preactivations; activations are fully lane-local
// (lane (s,cb,gt) owns units 16cb+4n+gt of seq s). No LDS, no barriers.
__global__ __launch_bounds__(64, 1)
void lstm_seq_kernel(const float* __restrict__ x,
                     const float* __restrict__ Wih_f, const float* __restrict__ Whh_f,
                     const float* __restrict__ b_f,
                     const float* __restrict__ Wih_b, const float* __restrict__ Whh_b,
                     const float* __restrict__ b_b,
                     float* __restrict__ hidden)
{
    const int bid  = blockIdx.x;           // 0..255
    const int dir  = bid >> 7;             // 0 = fwd, 1 = bwd
    const int bb0  = (bid & 127) * SPW;    // first of 8 contiguous batch rows
    const int lane = threadIdx.x;
    const int s    = lane & 7;             // sequence within group
    const int cb   = (lane >> 3) & 1;      // unit half (0: u0-15, 1: u16-31)
    const int gt   = lane >> 4;            // row-group / B k-group

    const float* __restrict__ Wih  = dir ? Wih_b : Wih_f;
    const float* __restrict__ Whh  = dir ? Whh_b : Whh_f;
    const float* __restrict__ bias = dir ? b_b   : b_f;

    const float LOG2E = 1.4426950408889634f;
    const float L2E2  = 2.0f * LOG2E;

    // ---- A fragments (unit-interleaved rows, K-permuted Whh, pre-scaled) --
    // A row: lane&15 -> gate=rit&3, unit-subrow=rit>>2; tile T -> unit 4T+sub.
    // k (slice0) = 8*gt+j: k<16 -> Wih[.][k]; k>=16 -> Whh[.][perm(k-16)]
    // k (slice1) = 32+8*gt+j: <48 -> Whh[.][perm(k-16)]; else 0.
    // perm(p) = 16*(p>>4) + 4*(p&3) + ((p>>2)&3)  [matches act-lane packing]
    const int rit   = lane & 15;
    const int gateA = rit & 3;
    const int gtA   = rit >> 2;
    const float scA = (gateA == 2) ? L2E2 : LOG2E;

    v8h aw0[8], aw1[8];
#pragma unroll
    for (int T = 0; T < 8; ++T) {
        const int orow = 32 * gateA + 4 * T + gtA;   // PyTorch row of this A row
        v8h t0, t1;
#pragma unroll
        for (int j = 0; j < 8; ++j) {
            float v0, v1;
            if (gt < 2) {
                v0 = Wih[orow * FF + 8 * gt + j];
                const int p2 = 8 * gt + j;                   // 0..15
                const int u1 = 16 + 4 * (p2 & 3) + (p2 >> 2);
                v1 = Whh[orow * HH + u1];
            } else {
                const int p  = 8 * (gt - 2) + j;             // 0..15
                const int u0 = 4 * (p & 3) + (p >> 2);
                v0 = Whh[orow * HH + u0];
                v1 = 0.0f;
            }
            t0[j] = (f16)(v0 * scA);
            t1[j] = (f16)(v1 * scA);
        }
        aw0[T] = t0; aw1[T] = t1;
    }

    // bias via the C operand: Cb[T][r] = bias of gate r, unit 4T+gt
    f32x4 Cb[8];
#pragma unroll
    for (int T = 0; T < 8; ++T) {
        Cb[T] = (f32x4){ bias[     4 * T + gt] * LOG2E,
                         bias[32 + 4 * T + gt] * LOG2E,
                         bias[64 + 4 * T + gt] * L2E2,
                         bias[96 + 4 * T + gt] * LOG2E };
    }

    // ---- bpermute source lanes for the h-gather (per destination g) ----
    // g=2: units 0-15 from lanes s, s+16; g=3: from s+32, s+48 (b0 slice)
    // g=0: units 16-23 from s+8, s+24;  g=1: 24-31 from s+40, s+56 (b1 slice)
    const int base1 = (gt == 0) ? 8 : (gt == 1) ? 40 : (gt == 2) ? 0 : 32;
    const int aAdr  = (base1 + s) * 4;
    const int bAdr  = aAdr + 64;           // partner lane +16
    const bool sel2 = (gt < 2);

    // ---- x register prefetch (2 steps deep); cols 8-15 duplicate seqs ----
    const ptrdiff_t tstep = (ptrdiff_t)(dir ? -(BB * FF) : (BB * FF));
    const float* xp = x + (size_t)(dir ? (TT - 1) : 0) * (BB * FF)
                        + (size_t)(bb0 + s) * FF + 8 * (gt & 1);
    float4 fA0 = *(const float4*)xp, fA1 = *(const float4*)(xp + 4);
    xp += tstep;
    float4 fB0 = *(const float4*)xp, fB1 = *(const float4*)(xp + 4);
    xp += tstep;

    float cp0 = 0.f, cp1 = 0.f, cp2 = 0.f, cp3 = 0.f;   // cp = 2log2e * c
    float h0 = 0.f, h1 = 0.f, h2 = 0.f, h3 = 0.f;
    int pkL = 0, pkH = 0;                                // packed f16 h pairs

    for (int n = 0; n < TT; n += 2) {
        STEP(fA0, fA1, (n + 2 < TT))
        STEP(fB0, fB1, (n + 3 < TT))
    }

    // lane (s,cb,gt) holds h of units 16cb+4n+gt, n=0..3
    float* hout = hidden + (size_t)(bb0 + s) * 64 + dir * HH + 16 * cb + gt;
    hout[0] = h0; hout[4] = h1; hout[8] = h2; hout[12] = h3;
}

// FC1 + per-block partial of FC2. Grid: 32 blocks x 256 threads.
__global__ __launch_bounds__(256)
void fc_partial_kernel(const float* __restrict__ hidden,
                       const float* __restrict__ Wfh, const float* __restrict__ bfh,
                       const float* __restrict__ Wfo,
                       float* __restrict__ partials)
{
    __shared__ float wsh[OO * 64];
    const int tid = threadIdx.x;
    for (int i = tid; i < OO * 64; i += 256) wsh[i] = Wfh[i];
    __syncthreads();

    const int r   = tid >> 3;
    const int o   = tid & 7;
    const int row = blockIdx.x * 32 + r;

    const float* hrow = hidden + (size_t)row * 64;
    float acc = bfh[o];
#pragma unroll
    for (int j = 0; j < 64; ++j) acc += hrow[j] * wsh[o * 64 + j];

    const int fidx = blockIdx.x * 256 + tid;

    float pv[OO];
#pragma unroll
    for (int o2 = 0; o2 < OO; ++o2) pv[o2] = Wfo[(size_t)o2 * (BB * OO) + fidx] * acc;

    __shared__ float red[4][OO];
#pragma unroll
    for (int o2 = 0; o2 < OO; ++o2) {
        float v = pv[o2];
        for (int off = 32; off > 0; off >>= 1) v += __shfl_down(v, off);
        if ((tid & 63) == 0) red[tid >> 6][o2] = v;
    }
    __syncthreads();
    if (tid < OO) {
        partials[blockIdx.x * OO + tid] =
            red[0][tid] + red[1][tid] + red[2][tid] + red[3][tid];
    }
}

__global__ void finalize_kernel(const float* __restrict__ partials,
                                const float* __restrict__ bfo,
                                float* __restrict__ out)
{
    __shared__ float sbuf[OO];
    const int tid = threadIdx.x;
    if (tid < OO) {
        float acc = bfo[tid];
        for (int b = 0; b < 32; ++b) acc += partials[b * OO + tid];
        sbuf[tid] = acc;
    }
    __syncthreads();
    if (tid == 0) {
        float m = sbuf[0];
        for (int i = 1; i < OO; ++i) m = fmaxf(m, sbuf[i]);
        float e[OO], sum = 0.0f;
        for (int i = 0; i < OO; ++i) { e[i] = expf(sbuf[i] - m); sum += e[i]; }
        for (int i = 0; i < OO; ++i) out[i] = e[i] / sum;
    }
}

extern "C" void kernel_launch(void* const* d_in, const int* in_sizes, int n_in,
                              void* d_out, int out_size, void* d_ws, size_t ws_size,
                              hipStream_t stream) {
    const float* x     = (const float*)d_in[0];
    const float* Wih_f = (const float*)d_in[1];
    const float* Whh_f = (const float*)d_in[2];
    const float* b_f   = (const float*)d_in[3];
    const float* Wih_b = (const float*)d_in[4];
    const float* Whh_b = (const float*)d_in[5];
    const float* b_b   = (const float*)d_in[6];
    const float* Wfh   = (const float*)d_in[7];
    const float* bfh   = (const float*)d_in[8];
    const float* Wfo   = (const float*)d_in[9];
    const float* bfo   = (const float*)d_in[10];

    float* hidden   = (float*)d_ws;
    float* partials = hidden + (size_t)BB * 64;

    lstm_seq_kernel<<<2 * BB / SPW, 64, 0, stream>>>(x, Wih_f, Whh_f, b_f,
                                                     Wih_b, Whh_b, b_b, hidden);
    fc_partial_kernel<<<32, 256, 0, stream>>>(hidden, Wfh, bfh, Wfo, partials);
    finalize_kernel<<<1, 64, 0, stream>>>(partials, bfo, (float*)d_out);
}

// Round 17
// 173.726 us; speedup vs baseline: 1.5007x; 1.5007x over previous
//
#include <hip/hip_runtime.h>

#define TT 512
#define BB 1024
#define FF 16
#define HH 32
#define OO 8
#define CH 16             // timesteps per x-chunk
#define NC (TT / CH)      // 32 chunks
#define NG 128            // gate rows (4*HH)

typedef _Float16 f16;
typedef f16 v2h __attribute__((ext_vector_type(2)));
typedef f16 v4h __attribute__((ext_vector_type(4)));
typedef f16 v8h __attribute__((ext_vector_type(8)));
typedef float f32x4 __attribute__((ext_vector_type(4)));
typedef int   v2i  __attribute__((ext_vector_type(2)));

__device__ __forceinline__ float rcp_fast(float x) { return __builtin_amdgcn_rcpf(x); }
// inputs PRE-SCALED by log2e (resp. 2*log2e) -> plain exp2
__device__ __forceinline__ float sigm2(float y) {
    return rcp_fast(1.0f + __builtin_amdgcn_exp2f(-y));
}
__device__ __forceinline__ float fdot2(v2h a, v2h b, float c) {
    return __builtin_amdgcn_fdot2(a, b, c, false);
}
__device__ __forceinline__ v2h i2h(int s) { return __builtin_bit_cast(v2h, s); }

// cross-half exchange WITHOUT a DS op (gfx950 VALU permlane).
__device__ __forceinline__ float xhalf_swap(float v) {
#if __has_builtin(__builtin_amdgcn_permlane32_swap)
    int pi = __float_as_int(v);
    v2i sw = __builtin_amdgcn_permlane32_swap(pi, pi, false, false);
    return __int_as_float(sw.x);
#else
    return __shfl_xor(v, 32);
#endif
}

// One LSTM timestep. gx consumed from carried prefetch regs (pgx0/pgx1,
// loaded one full step earlier); next step's loads issued at the top.
// setprio: 1 during the issue-dense dot block, 0 during the serial tail.
// cp carries c' = 2*log2e*c (tanh scale folded into lo-half pm/pa).
#define LSTEP(nptr, ntt)                                                       \
  {                                                                            \
    const int nxm = ((ntt) & 7) << 2;                                          \
    const float ngx0 = (nptr)[(ntt) * NG + (r0 ^ nxm)];                        \
    const float ngx1 = (nptr)[(ntt) * NG + (r1 ^ nxm)];                        \
    __builtin_amdgcn_s_setprio(1);                                             \
    float B0 = fdot2(i2h(hs[0]), w0h[0], pb0);                                 \
    float B1 = fdot2(i2h(hs[0]), w1h[0], pb1);                                 \
    float C0 = fdot2(i2h(hs[8]), w0h[8], pgx0);                                \
    float C1 = fdot2(i2h(hs[8]), w1h[8], pgx1);                                \
    _Pragma("unroll")                                                          \
    for (int j = 1; j < 8; ++j) {                                              \
      B0 = fdot2(i2h(hs[j]),     w0h[j],     B0);                              \
      B1 = fdot2(i2h(hs[j]),     w1h[j],     B1);                              \
      C0 = fdot2(i2h(hs[8 + j]), w0h[8 + j], C0);                              \
      C1 = fdot2(i2h(hs[8 + j]), w1h[8 + j], C1);                              \
    }                                                                          \
    __builtin_amdgcn_s_setprio(0);                                             \
    const float g0 = B0 + C0;                                                  \
    const float g1 = B1 + C1;                                                  \
    const float s0 = sigm2(g0);                /* si (lo) / sf (hi) */         \
    const float s1 = fmaf(sigm2(g1), pm, pa);  /* tg' (lo) / so (hi) */        \
    const float prod = s0 * s1;                                                \
    const float recv = xhalf_swap(prod);                                       \
    cp = fmaf(s0, cp, recv);                   /* hi: 2log2e*(sf*c+si*tg) */   \
    const float th = fmaf(2.0f, sigm2(cp), -1.0f);   /* tanh(c) */             \
    h = s1 * th;                               /* hi: so*tanh(c) */            \
    const int hn = __builtin_amdgcn_mov_dpp(__float_as_int(h),                 \
                                            0xB1, 0xF, 0xF, true);             \
    auto pk = __builtin_amdgcn_cvt_pkrtz(h, __int_as_float(hn));               \
    const int pki = __builtin_bit_cast(int, pk);                               \
    _Pragma("unroll")                                                          \
    for (int m = 0; m < HH / 2; ++m)                                           \
      hs[m] = __builtin_amdgcn_readlane(pki, 32 + 2 * m);                      \
    pgx0 = ngx0; pgx1 = ngx1;                                                  \
  }

// One wave per block, one sequence per wave (2048 blocks, 2 waves/SIMD).
// Validated structure (best: 173.9us total): row-split full-k dots vs SGPR
// h-broadcast; x-part batched per 16-step chunk on the matrix pipe into
// XOR-swizzled LDS; deferred staging at tt==11; no barriers (single-wave
// block, DS in-order); one-step gx register prefetch; wave anti-phasing.
__global__ __launch_bounds__(64, 2)
void lstm_seq_kernel(const float* __restrict__ x,
                     const float* __restrict__ Wih_f, const float* __restrict__ Whh_f,
                     const float* __restrict__ b_f,
                     const float* __restrict__ Wih_b, const float* __restrict__ Whh_b,
                     const float* __restrict__ b_b,
                     float* __restrict__ hidden)
{
    const int bid  = blockIdx.x;          // 0..2047
    const int dir  = bid >> 10;           // 0 = fwd, 1 = bwd
    const int bb   = bid & (BB - 1);      // batch row
    const int lane = threadIdx.x;
    const int hi   = lane >> 5;           // 0: rows {i,g}   1: rows {f,o}
    const int kk   = lane & 31;

    const float* __restrict__ Wih  = dir ? Wih_b : Wih_f;
    const float* __restrict__ Whh  = dir ? Whh_b : Whh_f;
    const float* __restrict__ bias = dir ? b_b   : b_f;

    const float LOG2E = 1.4426950408889634f;
    const float L2E2  = 2.0f * LOG2E;

    const int r0 = kk + hi * HH;      // i (hi=0) / f (hi=1)
    const int r1 = r0 + 2 * HH;       // g (hi=0) / o (hi=1)
    const float sc0 = LOG2E;
    const float sc1 = hi ? LOG2E : L2E2;
    // lo half: tg' = (2log2e)*tanh(g) = sigm2(g1)*2*L2E2 - L2E2 (c'-folding)
    const float pm = hi ? 1.0f : 2.0f * L2E2;
    const float pa = hi ? 0.0f : -L2E2;

    // ---- recurrent weights: 2 rows x 16 h-pairs, f16, pre-scaled ----
    v2h w0h[HH / 2], w1h[HH / 2];
#pragma unroll
    for (int q = 0; q < HH / 4; ++q) {
        float4 a = ((const float4*)(Whh + r0 * HH))[q];
        w0h[2*q]   = (v2h){(f16)(a.x * sc0), (f16)(a.y * sc0)};
        w0h[2*q+1] = (v2h){(f16)(a.z * sc0), (f16)(a.w * sc0)};
        float4 b2 = ((const float4*)(Whh + r1 * HH))[q];
        w1h[2*q]   = (v2h){(f16)(b2.x * sc1), (f16)(b2.y * sc1)};
        w1h[2*q+1] = (v2h){(f16)(b2.z * sc1), (f16)(b2.w * sc1)};
    }
    const float pb0 = bias[r0] * sc0;
    const float pb1 = bias[r1] * sc1;

    // ---- MFMA A-fragments for the x-GEMM (validated r8/r9) ----
    v8h awx[8];
#pragma unroll
    for (int T = 0; T < 8; ++T) {
        v8h t = {(f16)0,(f16)0,(f16)0,(f16)0,(f16)0,(f16)0,(f16)0,(f16)0};
        if (lane < 32) {
            const int gate = T * 16 + (lane & 15);
            const float sc = (gate >= 64 && gate < 96) ? L2E2 : LOG2E;
            const float* wrow = Wih + gate * FF + (lane >> 4) * 8;
#pragma unroll
            for (int j = 0; j < 8; ++j) t[j] = (f16)(wrow[j] * sc);
        }
        awx[T] = t;
    }

    __shared__ __align__(16) f16   xsb[2 * CH * FF];   // 1 KB: x chunks (f16)
    __shared__ __align__(16) float gxb[2 * CH * NG];   // 16 KB: x-gates (f32)

    // ---- x chunk staging: lane (sl,wl) covers step sl, quarter wl ----
    const int sl = lane >> 2;
    const int wl = lane & 3;
    const int t0 = dir ? (TT - 1 - sl) : sl;
    const float* xp = x + (size_t)t0 * (BB * FF) + (size_t)bb * FF + wl * 4;
    const ptrdiff_t dstep = (dir ? -(ptrdiff_t)CH : (ptrdiff_t)CH) * (BB * FF);

    // MFMA scatter base: col (lane&15)=step, row (lane>>4)*4+reg=gate
    const int mst = lane & 15;
    const int mq  = (lane >> 4) * 4;
    const int mxr = (mst & 7) << 2;

    // prologue: stage chunk 0, compute gx[0], prefetch chunk 1
    {
        float4 f0 = *(const float4*)xp;
        *(v4h*)(xsb + sl * FF + wl * 4) =
            (v4h){(f16)f0.x, (f16)f0.y, (f16)f0.z, (f16)f0.w};
    }
    xp += dstep;
    {
        v8h bx0 = {(f16)0,(f16)0,(f16)0,(f16)0,(f16)0,(f16)0,(f16)0,(f16)0};
        if (lane < 32)
            bx0 = *(const v8h*)(xsb + (lane & 15) * FF + (lane >> 4) * 8);
        float* gw = gxb + mst * NG;
#pragma unroll
        for (int T = 0; T < 8; ++T) {
            f32x4 acc = __builtin_amdgcn_mfma_f32_16x16x32_f16(
                awx[T], bx0, (f32x4){0.f, 0.f, 0.f, 0.f}, 0, 0, 0);
            *(f32x4*)(gw + ((mq + T * 16) ^ mxr)) = acc;
        }
    }
    float4 nf = *(const float4*)xp;   // chunk 1
    xp += dstep;

    float cp = 0.0f, h = 0.0f;        // cp = 2*log2e * c
    int hs[HH / 2];                   // packed f16 h-pairs (wave-uniform)
#pragma unroll
    for (int m = 0; m < HH / 2; ++m) hs[m] = 0;

    // prime the gx prefetch pipeline: chunk 0, step 0
    float pgx0 = gxb[r0];
    float pgx1 = gxb[r1];

    // ---- wave anti-phasing: offset one wave of each SIMD pair by ~half a
    // step (no barriers anywhere -> the offset persists for all 512 steps).
    if ((bid ^ (bid >> 10)) & 1) __builtin_amdgcn_s_sleep(7);   // ~448 cyc

    for (int ci = 0; ci < NC; ++ci) {
        const int bufc = ci & 1;
        const int bufn = bufc ^ 1;
        const bool more = (ci + 1 < NC);

        // chunk top: stage next x into LDS, read bx (long slack), issue
        // the next global prefetch (covered by ~28 steps of compute)
        v8h bx = {(f16)0,(f16)0,(f16)0,(f16)0,(f16)0,(f16)0,(f16)0,(f16)0};
        if (more) {
            *(v4h*)(xsb + bufn * (CH * FF) + sl * FF + wl * 4) =
                (v4h){(f16)nf.x, (f16)nf.y, (f16)nf.z, (f16)nf.w};
            if (lane < 32)
                bx = *(const v8h*)(xsb + bufn * (CH * FF) + (lane & 15) * FF + (lane >> 4) * 8);
            if (ci + 2 < NC) { nf = *(const float4*)xp; xp += dstep; }
        }

        const float* gxc = gxb + bufc * (CH * NG);
        const float* gxn = gxb + bufn * (CH * NG);

        // steps 0..11: prefetch next step from the current chunk
#pragma unroll
        for (int tt = 0; tt < 12; ++tt) LSTEP(gxc, tt + 1)

        // deferred staging compute: 8 MFMA + gxb writes for chunk ci+1.
        // Step-12 prefetch (issued in step 11) precedes these writes in DS
        // program order and reads the CURRENT chunk — safe. The step-0
        // next-chunk prefetch (issued in step 15) follows them — safe.
        if (more) {
            float* gw = gxb + bufn * (CH * NG) + mst * NG;
#pragma unroll
            for (int T = 0; T < 8; ++T) {
                f32x4 acc = __builtin_amdgcn_mfma_f32_16x16x32_f16(
                    awx[T], bx, (f32x4){0.f, 0.f, 0.f, 0.f}, 0, 0, 0);
                *(f32x4*)(gw + ((mq + T * 16) ^ mxr)) = acc;
            }
        }

        // steps 12..14: still prefetching within the current chunk
#pragma unroll
        for (int tt = 12; tt < CH - 1; ++tt) LSTEP(gxc, tt + 1)

        // step 15: prefetch step 0 of the NEXT chunk (clamped on last)
        if (more) { LSTEP(gxn, 0) }
        else      { LSTEP(gxc, 0) }
    }

    if (hi) hidden[(size_t)bb * 64 + dir * HH + kk] = h;
}

// FC1 + per-block partial of FC2. Grid: 32 blocks x 256 threads.
__global__ __launch_bounds__(256)
void fc_partial_kernel(const float* __restrict__ hidden,
                       const float* __restrict__ Wfh, const float* __restrict__ bfh,
                       const float* __restrict__ Wfo,
                       float* __restrict__ partials)
{
    __shared__ float wsh[OO * 64];
    const int tid = threadIdx.x;
    for (int i = tid; i < OO * 64; i += 256) wsh[i] = Wfh[i];
    __syncthreads();

    const int r   = tid >> 3;
    const int o   = tid & 7;
    const int row = blockIdx.x * 32 + r;

    const float* hrow = hidden + (size_t)row * 64;
    float acc = bfh[o];
#pragma unroll
    for (int j = 0; j < 64; ++j) acc += hrow[j] * wsh[o * 64 + j];

    const int fidx = blockIdx.x * 256 + tid;

    float pv[OO];
#pragma unroll
    for (int o2 = 0; o2 < OO; ++o2) pv[o2] = Wfo[(size_t)o2 * (BB * OO) + fidx] * acc;

    __shared__ float red[4][OO];
#pragma unroll
    for (int o2 = 0; o2 < OO; ++o2) {
        float v = pv[o2];
        for (int off = 32; off > 0; off >>= 1) v += __shfl_down(v, off);
        if ((tid & 63) == 0) red[tid >> 6][o2] = v;
    }
    __syncthreads();
    if (tid < OO) {
        partials[blockIdx.x * OO + tid] =
            red[0][tid] + red[1][tid] + red[2][tid] + red[3][tid];
    }
}

__global__ void finalize_kernel(const float* __restrict__ partials,
                                const float* __restrict__ bfo,
                                float* __restrict__ out)
{
    __shared__ float s[OO];
    const int tid = threadIdx.x;
    if (tid < OO) {
        float acc = bfo[tid];
        for (int b = 0; b < 32; ++b) acc += partials[b * OO + tid];
        s[tid] = acc;
    }
    __syncthreads();
    if (tid == 0) {
        float m = s[0];
        for (int i = 1; i < OO; ++i) m = fmaxf(m, s[i]);
        float e[OO], sum = 0.0f;
        for (int i = 0; i < OO; ++i) { e[i] = expf(s[i] - m); sum += e[i]; }
        for (int i = 0; i < OO; ++i) out[i] = e[i] / sum;
    }
}

extern "C" void kernel_launch(void* const* d_in, const int* in_sizes, int n_in,
                              void* d_out, int out_size, void* d_ws, size_t ws_size,
                              hipStream_t stream) {
    const float* x     = (const float*)d_in[0];
    const float* Wih_f = (const float*)d_in[1];
    const float* Whh_f = (const float*)d_in[2];
    const float* b_f   = (const float*)d_in[3];
    const float* Wih_b = (const float*)d_in[4];
    const float* Whh_b = (const float*)d_in[5];
    const float* b_b   = (const float*)d_in[6];
    const float* Wfh   = (const float*)d_in[7];
    const float* bfh   = (const float*)d_in[8];
    const float* Wfo   = (const float*)d_in[9];
    const float* bfo   = (const float*)d_in[10];

    float* hidden   = (float*)d_ws;
    float* partials = hidden + (size_t)BB * 64;

    lstm_seq_kernel<<<2 * BB, 64, 0, stream>>>(x, Wih_f, Whh_f, b_f,
                                               Wih_b, Whh_b, b_b, hidden);
    fc_partial_kernel<<<32, 256, 0, stream>>>(hidden, Wfh, bfh, Wfo, partials);
    finalize_kernel<<<1, 64, 0, stream>>>(partials, bfo, (float*)d_out);
}